// Round 1
// baseline (275.029 us; speedup 1.0000x reference)
//
#include <hip/hip_runtime.h>
#include <math.h>

// LSTM: N=32768 seqs, T=600, H=5, input dim 1.
// R12 = occupancy restructure: 4 lanes/seq (was 2), 16 seqs/block, grid 2048
// -> 2 waves/SIMD (was exactly 1). Rationale: R11 counters showed
// OccupancyPercent 11% (1 wave/SIMD), VALUBusy 72%, ~320 of ~500 busy
// cyc/step in the trans pipe (20 exp2/rcp per step) and ~28% dependency-stall
// idle. Trans and VALU are separate pipes: a second resident wave fills the
// idle and issues its matvec/DPP work under the other wave's trans shadow.
// Per-seq trans instr count is UNCHANGED by the restructure (0.625/seq/step):
//   per lane: pair {i_l,g_l} (2 exp2 + 1 rcp), 3-way shared rcp over
//   {f_l,o_l,e_l} (3 exp2 + 1 rcp), paired c-tanh {c_l,c4} (2 exp2 + 1 rcp)
//   = 10 trans/lane/step; matvec halves to 12 pk-fma + 6 fma per lane.
// Row map (lane l of quad): pA={i_l(row l), g_l(row 10+l)},
//   pB={f_l(row 5+l), o_l(row 15+l)}, extra e_l = row 4+5l
//   (l=0:i4, 1:f4, 2:g4, 3:o4). Units 0-3: c-update fully lane-local (zero
//   shuffles). Unit 4: 4 quad_perm broadcasts of e-activations, c4 duplicated
//   on all 4 lanes; its tanh pairs with the local c-tanh's rcp (near-free).
// H redistribution: 4 quad_perm broadcasts (h_l from lane l); h4 already
// uniform. All cross-lane traffic is quad_perm DPP (4-lane groups = 1 seq).
// Same scaled-space math as R11: g-rows pre-scaled -2log2e, others -log2e;
// g-activation emits g~ = -2log2e*tanh(g); c tracked in c~ = -2log2e*c space.
// Same dbuf LDS tile staging + global->VGPR prefetch + 4-step-ahead LDS read.

#define LOG2E 1.44269504088896340736f

typedef float v2f __attribute__((ext_vector_type(2)));

constexpr int T_ = 600;
constexpr int SEQ_PER_BLOCK = 16;
constexpr int TTILE = 64;
constexpr int NTILES = (T_ + TTILE - 1) / TTILE;   // 10 (last tile: 24 steps)
constexpr int LDS_STRIDE = 68;   // 16B-aligned rows; 2-way bank alias only
constexpr int XBUF = SEQ_PER_BLOCK * LDS_STRIDE;

__device__ __forceinline__ float fast_rcp(float v)  { return __builtin_amdgcn_rcpf(v); }
__device__ __forceinline__ float fast_exp2(float v) { return __builtin_amdgcn_exp2f(v); }

// quad_perm DPP broadcasts within each 4-lane group:
// 0x00=[0,0,0,0] 0x55=[1,1,1,1] 0xAA=[2,2,2,2] 0xFF=[3,3,3,3]
template <int CTRL>
__device__ __forceinline__ float dpp_q(float v) {
    const int x = __float_as_int(v);
    return __int_as_float(__builtin_amdgcn_update_dpp(x, x, CTRL, 0xF, 0xF, false));
}

__global__ __launch_bounds__(64, 2) void lstm_kernel(
    const float* __restrict__ x,
    const float* __restrict__ w_ih,   // (20,1)
    const float* __restrict__ w_hh,   // (20,5)
    const float* __restrict__ b_ih,   // (20,)
    const float* __restrict__ b_hh,   // (20,)
    const float* __restrict__ fc_w,   // (15,5)
    const float* __restrict__ fc_b,   // (15,)
    const float* __restrict__ out_w,  // (1,15)
    const float* __restrict__ out_b,  // (1,)
    float* __restrict__ out)          // (N,1)
{
    __shared__ float xs[2 * XBUF];

    const int lane = threadIdx.x;     // 0..63
    const int s    = lane >> 2;       // local sequence 0..15
    const int l    = lane & 3;        // quad lane 0..3

    // ---- row tables (rows: i=0..4, f=5..9, g=10..14, o=15..19) ----
    const int rA0 = l;          // i_l (sigmoid)
    const int rA1 = 10 + l;     // g_l (tanh)
    const int rB0 = 5 + l;      // f_l (sigmoid)
    const int rB1 = 15 + l;     // o_l (sigmoid)
    const int rE  = 4 + 5 * l;  // extra: l=0:i4 l=1:f4 l=2:g4 l=3:o4
    const float sSig = -LOG2E;
    const float sTan = -2.0f * LOG2E;
    const float sE   = (l == 2) ? sTan : sSig;

    v2f wihA, wihB, bbA, bbB, whhA[5], whhB[5];
    float wihE, bbE, whhE[5];
    {
        wihA = (v2f){ w_ih[rA0] * sSig, w_ih[rA1] * sTan };
        wihB = (v2f){ w_ih[rB0] * sSig, w_ih[rB1] * sSig };
        wihE = w_ih[rE] * sE;
        bbA  = (v2f){ (b_ih[rA0] + b_hh[rA0]) * sSig,
                      (b_ih[rA1] + b_hh[rA1]) * sTan };
        bbB  = (v2f){ (b_ih[rB0] + b_hh[rB0]) * sSig,
                      (b_ih[rB1] + b_hh[rB1]) * sSig };
        bbE  = (b_ih[rE] + b_hh[rE]) * sE;
#pragma unroll
        for (int k = 0; k < 5; ++k) {
            whhA[k] = (v2f){ w_hh[rA0 * 5 + k] * sSig, w_hh[rA1 * 5 + k] * sTan };
            whhB[k] = (v2f){ w_hh[rB0 * 5 + k] * sSig, w_hh[rB1 * 5 + k] * sSig };
            whhE[k] = w_hh[rE * 5 + k] * sE;
        }
    }

    float H[5] = {0.f, 0.f, 0.f, 0.f, 0.f};  // true h, uniform across quad
    float cL = 0.f;   // c~ of unit l (lane-local)
    float c4 = 0.f;   // c~ of unit 4 (duplicated on all 4 lanes, uniform)

    const float* xblk = x + (size_t)(blockIdx.x * SEQ_PER_BLOCK) * T_;

    auto step = [&](float xt) {
        // ---- gates: 12 pk-fma + 6 fma ----
        const v2f x2 = (v2f){ xt, xt };
        v2f gA = x2 * wihA + bbA;
        v2f gB = x2 * wihB + bbB;
        float gE = fmaf(xt, wihE, bbE);
#pragma unroll
        for (int k = 0; k < 5; ++k) {
            const v2f h2 = (v2f){ H[k], H[k] };
            gA += h2 * whhA[k];
            gB += h2 * whhB[k];
            gE  = fmaf(H[k], whhE[k], gE);
        }
        // ---- activations: 5 exp2 + 2 rcp ----
        const float dAx = 1.0f + fast_exp2(gA.x);
        const float dAy = 1.0f + fast_exp2(gA.y);
        const float dBx = 1.0f + fast_exp2(gB.x);
        const float dBy = 1.0f + fast_exp2(gB.y);
        const float dE  = 1.0f + fast_exp2(gE);
        const float rpA = fast_rcp(dAx * dAy);
        const float mB  = dBx * dBy;
        const float rp3 = fast_rcp(mB * dE);           // shared over f,o,e
        const float i_l = rpA * dAy;                   // sigmoid(i_l)
        const float gt  = fmaf(rpA * dAx, -4.0f * LOG2E, 2.0f * LOG2E); // g~_l
        const float f_l = rp3 * (dBy * dE);            // sigmoid(f_l)
        const float o_l = rp3 * (dBx * dE);            // sigmoid(o_l)
        const float vE  = rp3 * mB;   // lanes 0,1,3: sigmoid(e); lane2: sig(2*g4)
        const float vEg = fmaf(vE, -4.0f * LOG2E, 2.0f * LOG2E);  // g~4 on lane2
        // ---- unit-4 gate broadcasts (4 DPP) ----
        const float i4 = dpp_q<0x00>(vE);
        const float f4 = dpp_q<0x55>(vE);
        const float g4 = dpp_q<0xAA>(vEg);
        const float o4 = dpp_q<0xFF>(vE);
        // ---- c updates in c~ space ----
        cL = fmaf(f_l, cL, i_l * gt);
        c4 = fmaf(f4, c4, i4 * g4);
        // ---- tanh(c): 2 exp2 + 1 rcp (paired) ----
        const float dL = 1.0f + fast_exp2(cL);
        const float d4 = 1.0f + fast_exp2(c4);
        const float q  = fast_rcp(dL * d4);
        const float tL = fmaf(q * d4, 2.0f, -1.0f);
        const float t4 = fmaf(q * dL, 2.0f, -1.0f);
        // ---- h and redistribution (4 DPP) ----
        const float hL = o_l * tL;
        H[4] = o4 * t4;                 // uniform (all inputs uniform)
        H[0] = dpp_q<0x00>(hL);
        H[1] = dpp_q<0x55>(hL);
        H[2] = dpp_q<0xAA>(hL);
        H[3] = dpp_q<0xFF>(hL);
    };

    const int rrow = lane >> 4;         // 0..3
    const int ccol = (lane & 15) << 2;  // 0,4,...,60

    // ---- prologue: stage tile 0 into buffer 0 (16 rows x 64 cols) ----
#pragma unroll
    for (int it = 0; it < 4; ++it) {
        const int r = it * 4 + rrow;
        const float4 v = *(const float4*)(xblk + (size_t)r * T_ + ccol);
        *(float4*)&xs[r * LDS_STRIDE + ccol] = v;
    }
    __syncthreads();

    for (int tile = 0; tile < NTILES; ++tile) {
        // ---- issue next-tile global loads NOW (unconditional, clamped) ----
        const int tpf = (tile + 1 < NTILES) ? (tile + 1) : (NTILES - 1);
        const int cpf = (tpf * TTILE + ccol <= T_ - 4) ? (tpf * TTILE + ccol) : (T_ - 4);
        float4 pf[4];
#pragma unroll
        for (int it = 0; it < 4; ++it) {
            const int r = it * 4 + rrow;
            pf[it] = *(const float4*)(xblk + (size_t)r * T_ + cpf);
        }
        // ---- compute current tile, LDS reads prefetched 4 steps ahead ----
        const int t0i   = tile * TTILE;
        const int steps = (T_ - t0i >= TTILE) ? TTILE : (T_ - t0i);   // 64 or 24
        const float* xr = &xs[(tile & 1) * XBUF + s * LDS_STRIDE];
        float4 cur = *(const float4*)&xr[0];
        for (int tt = 0; tt < steps; tt += 4) {
            const float4 nxt = *(const float4*)&xr[tt + 4];  // pad at edge, unused
            step(cur.x);
            step(cur.y);
            step(cur.z);
            step(cur.w);
            cur = nxt;
        }
        // ---- stage prefetched tile into the other buffer ----
        float* xw = &xs[((tile + 1) & 1) * XBUF];
#pragma unroll
        for (int it = 0; it < 4; ++it) {
            const int r = it * 4 + rrow;
            *(float4*)&xw[r * LDS_STRIDE + ccol] = pf[it];
        }
        __syncthreads();
    }

    // ---- head: hid = H@fc_w.T + fc_b ; out = sigmoid(hid@out_w.T + out_b) ----
    if (l == 0) {
        float acc = out_b[0];
#pragma unroll
        for (int j = 0; j < 15; ++j) {
            float hid = fc_b[j];
#pragma unroll
            for (int k = 0; k < 5; ++k) hid = fmaf(H[k], fc_w[j * 5 + k], hid);
            acc = fmaf(hid, out_w[j], acc);
        }
        out[blockIdx.x * SEQ_PER_BLOCK + s] = fast_rcp(1.0f + fast_exp2(-acc * LOG2E));
    }
}

extern "C" void kernel_launch(void* const* d_in, const int* in_sizes, int n_in,
                              void* d_out, int out_size, void* d_ws, size_t ws_size,
                              hipStream_t stream) {
    const float* x    = (const float*)d_in[0];
    const float* w_ih = (const float*)d_in[1];
    const float* w_hh = (const float*)d_in[2];
    const float* b_ih = (const float*)d_in[3];
    const float* b_hh = (const float*)d_in[4];
    const float* fc_w = (const float*)d_in[5];
    const float* fc_b = (const float*)d_in[6];
    const float* out_w = (const float*)d_in[7];
    const float* out_b = (const float*)d_in[8];
    float* out = (float*)d_out;

    const int N = in_sizes[0] / T_;             // 32768
    const int grid = N / SEQ_PER_BLOCK;         // 2048 blocks -> 2 waves/SIMD
    hipLaunchKernelGGL(lstm_kernel, dim3(grid), dim3(64), 0, stream,
                       x, w_ih, w_hh, b_ih, b_hh, fc_w, fc_b, out_w, out_b, out);
}

// Round 2
// 256.417 us; speedup vs baseline: 1.0726x; 1.0726x over previous
//
#include <hip/hip_runtime.h>
#include <math.h>

// LSTM: N=32768 seqs, T=600, H=5, input dim 1.
// R13 = R11 base (2 lanes/seq, 32 seqs/wave, 1024 waves = 1/SIMD) + shared-rcp
// trans reduction. R12's occupancy experiment (4 lanes/seq, 2 waves/SIMD)
// FALSIFIED the trans/VALU-overlap theory: busy cycles grew additively with
// the extra VALU instrs (501->660 per 32 seqs/step) and dur regressed 14%.
// Issue cycles are the cost function; trans (16 cyc each) issue-blocks.
// R13 cuts gate rcps 5->2 via product-sharing:
//   6-way over pairs {0,1,2}: rcp(m0*m1*m2), recover 1/m_p by tree muls
//     (15 mul + 1 rcp vs 9 mul + 3 rcp: -20 cyc)
//   4-way over pairs {3,4}: (9 mul + 1 rcp vs 6 mul + 2 rcp: -10 cyc)
// Overflow-safe: d = 1+exp2(|g~|<=~23) -> 6-product <= ~2^78 << f32 max.
// c-tanh keeps 2 parallel rcps (tail latency), but h=o*tanh folded to
// h = fma(q*dB, 2o, -o) with 2o precomputed off-path: -8 cyc tail latency.
// Row assignment (per lane, 5 v2f pairs):
//   even: p0={i0,g0} p1={i1,g1} p2={i2,g2} p3={f0,o0} p4={f1,o1}
//   odd : p0={i3,g3} p1={i4,g4} p2={f2,o2} p3={f3,o3} p4={f4,o4}
// c-update units 0,1 (even) / 3,4 (odd) lane-local; unit 2 via 3 DPP
// broadcasts; H redistributed with 4 DPPs. g-rows pre-scaled -2log2e, others
// -log2e; g-activation emits g~ = -2log2e*tanh(g); c tracked in c~ space.
// Block = 64 = 1 wave = 32 seqs; grid = 1024 -> 1 wave/SIMD chip-wide.

#define LOG2E 1.44269504088896340736f

typedef float v2f __attribute__((ext_vector_type(2)));

constexpr int T_ = 600;
constexpr int SEQ_PER_BLOCK = 32;
constexpr int TTILE = 64;
constexpr int NTILES = (T_ + TTILE - 1) / TTILE;   // 10 (last tile: 24 steps)
constexpr int LDS_STRIDE = 68;   // 16B-aligned rows; 4-way bank alias on b128 (minor)
constexpr int XBUF = SEQ_PER_BLOCK * LDS_STRIDE;

__device__ __forceinline__ float fast_rcp(float v)  { return __builtin_amdgcn_rcpf(v); }
__device__ __forceinline__ float fast_exp2(float v) { return __builtin_amdgcn_exp2f(v); }

// quad_perm DPP: 0xA0 = [0,0,2,2] (even lane of pair -> both),
//                0xF5 = [1,1,3,3] (odd lane of pair -> both)
template <int CTRL>
__device__ __forceinline__ float dpp_q(float v) {
    const int x = __float_as_int(v);
    return __int_as_float(__builtin_amdgcn_update_dpp(x, x, CTRL, 0xF, 0xF, false));
}

__global__ __launch_bounds__(64, 1) void lstm_kernel(
    const float* __restrict__ x,
    const float* __restrict__ w_ih,   // (20,1)
    const float* __restrict__ w_hh,   // (20,5)
    const float* __restrict__ b_ih,   // (20,)
    const float* __restrict__ b_hh,   // (20,)
    const float* __restrict__ fc_w,   // (15,5)
    const float* __restrict__ fc_b,   // (15,)
    const float* __restrict__ out_w,  // (1,15)
    const float* __restrict__ out_b,  // (1,)
    float* __restrict__ out)          // (N,1)
{
    __shared__ float xs[2 * XBUF];

    const int lane = threadIdx.x;     // 0..63
    const int s    = lane >> 1;       // local sequence 0..31
    const int half = lane & 1;
    const int seq  = blockIdx.x * SEQ_PER_BLOCK + s;

    // ---- row tables (rows: i=0..4, f=5..9, g=10..14, o=15..19) ----
    const int rloT[2][5] = {{0, 1, 2, 5, 6}, {3, 4, 7, 8, 9}};
    const int rhiT[2][5] = {{10, 11, 12, 15, 16}, {13, 14, 17, 18, 19}};
    const int gtT [2][5] = {{1, 1, 1, 0, 0}, {1, 1, 0, 0, 0}};   // hi-elem is g(tanh)?

    v2f wih2[5], bb2[5], whh2[5][5];
#pragma unroll
    for (int p = 0; p < 5; ++p) {
        const int rlo = rloT[half][p], rhi = rhiT[half][p];
        const float sl = -LOG2E;
        const float sh = gtT[half][p] ? (-2.0f * LOG2E) : (-LOG2E);
        wih2[p] = (v2f){ w_ih[rlo] * sl, w_ih[rhi] * sh };
        bb2[p]  = (v2f){ (b_ih[rlo] + b_hh[rlo]) * sl,
                         (b_ih[rhi] + b_hh[rhi]) * sh };
#pragma unroll
        for (int k = 0; k < 5; ++k)
            whh2[p][k] = (v2f){ w_hh[rlo * 5 + k] * sl, w_hh[rhi * 5 + k] * sh };
    }

    float H[5] = {0.f, 0.f, 0.f, 0.f, 0.f};   // true h, uniform on both lanes
    float cA = 0.f, cB = 0.f, cC = 0.f;       // c~ slots: even(c0,c1,c2) odd(c3,c4,c2)

    const float* xblk = x + (size_t)(blockIdx.x * SEQ_PER_BLOCK) * T_;

    auto step = [&](float xt) {
        const v2f x2 = (v2f){ xt, xt };
        v2f g2[5];
#pragma unroll
        for (int p = 0; p < 5; ++p) g2[p] = x2 * wih2[p] + bb2[p];
#pragma unroll
        for (int k = 0; k < 5; ++k) {
            const v2f h2 = (v2f){ H[k], H[k] };
#pragma unroll
            for (int p = 0; p < 5; ++p) g2[p] += h2 * whh2[p][k];
        }
        // ---- denominators: 10 exp2 + 10 add (packing floor) ----
        float dx[5], dy[5];
#pragma unroll
        for (int p = 0; p < 5; ++p) {
            dx[p] = 1.0f + fast_exp2(g2[p].x);
            dy[p] = 1.0f + fast_exp2(g2[p].y);
        }
        v2f act2[5];
        // ---- 6-way shared rcp over pairs {0,1,2}: 15 mul + 1 rcp ----
        {
            const float m0   = dx[0] * dy[0];
            const float m1   = dx[1] * dy[1];
            const float m2   = dx[2] * dy[2];
            const float m01  = m0 * m1;
            const float rp   = fast_rcp(m01 * m2);
            const float rp2  = rp * m01;    // 1/m2
            const float rp01 = rp * m2;     // 1/(m0*m1)
            const float rp0  = rp01 * m1;   // 1/m0
            const float rp1  = rp01 * m0;   // 1/m1
            act2[0].x = rp0 * dy[0];  act2[0].y = rp0 * dx[0];
            act2[1].x = rp1 * dy[1];  act2[1].y = rp1 * dx[1];
            act2[2].x = rp2 * dy[2];  act2[2].y = rp2 * dx[2];
        }
        // ---- 4-way shared rcp over pairs {3,4}: 9 mul + 1 rcp ----
        {
            const float m3  = dx[3] * dy[3];
            const float m4  = dx[4] * dy[4];
            const float rp  = fast_rcp(m3 * m4);
            const float rp3 = rp * m4;      // 1/m3
            const float rp4 = rp * m3;      // 1/m4
            act2[3].x = rp3 * dy[3];  act2[3].y = rp3 * dx[3];
            act2[4].x = rp4 * dy[4];  act2[4].y = rp4 * dx[4];
        }
        // ---- g~ adjust: hi elems of p0,p1 always; p2 only on even lanes ----
        act2[0].y = fmaf(act2[0].y, -4.0f * LOG2E, 2.0f * LOG2E);
        act2[1].y = fmaf(act2[1].y, -4.0f * LOG2E, 2.0f * LOG2E);
        if (half == 0)
            act2[2].y = fmaf(act2[2].y, -4.0f * LOG2E, 2.0f * LOG2E);

        const float PA = act2[0].x * act2[0].y;               // i*g~ : u0 / u3
        const float PB = act2[1].x * act2[1].y;               // u1 / u4
        const float P2 = dpp_q<0xA0>(act2[2].x * act2[2].y);  // i2*g~2 -> both
        const float f2 = dpp_q<0xF5>(act2[2].x);              // f2 -> both
        const float o2 = dpp_q<0xF5>(act2[2].y);              // o2 -> both
        cA = fmaf(act2[3].x, cA, PA);
        cB = fmaf(act2[4].x, cB, PB);
        cC = fmaf(f2, cC, P2);
        // off-critical-path doubles for the tail fma fold
        const float oA  = act2[3].y, oB = act2[4].y;
        const float oA2 = oA + oA;
        const float oB2 = oB + oB;
        const float o22 = o2 + o2;
        // ---- tanh(c~) tail: 3 exp2 + 2 parallel rcp, fma-folded h ----
        const float dA = 1.0f + fast_exp2(cA);
        const float dB = 1.0f + fast_exp2(cB);
        const float dC = 1.0f + fast_exp2(cC);
        const float q  = fast_rcp(dA * dB);
        const float rC = fast_rcp(dC);
        const float hA = fmaf(q * dB, oA2, -oA);   // oA*(2*sig-1)
        const float hB = fmaf(q * dA, oB2, -oB);
        H[2] = fmaf(rC, o22, -o2);
        H[0] = dpp_q<0xA0>(hA);
        H[1] = dpp_q<0xA0>(hB);
        H[3] = dpp_q<0xF5>(hA);
        H[4] = dpp_q<0xF5>(hB);
    };

    const int rrow = lane >> 4;         // 0..3
    const int ccol = (lane & 15) << 2;  // 0,4,...,60

    // ---- prologue: stage tile 0 into buffer 0 ----
#pragma unroll
    for (int it = 0; it < 8; ++it) {
        const int r = it * 4 + rrow;
        const float4 v = *(const float4*)(xblk + (size_t)r * T_ + ccol);
        *(float4*)&xs[r * LDS_STRIDE + ccol] = v;
    }
    __syncthreads();

    for (int tile = 0; tile < NTILES; ++tile) {
        // ---- issue next-tile global loads NOW (unconditional, clamped) ----
        const int tpf  = (tile + 1 < NTILES) ? (tile + 1) : (NTILES - 1);
        const int cpf  = (tpf * TTILE + ccol <= T_ - 4) ? (tpf * TTILE + ccol) : (T_ - 4);
        float4 pf[8];
#pragma unroll
        for (int it = 0; it < 8; ++it) {
            const int r = it * 4 + rrow;
            pf[it] = *(const float4*)(xblk + (size_t)r * T_ + cpf);
        }
        // ---- compute current tile, LDS reads prefetched 4 steps ahead ----
        const int t0i   = tile * TTILE;
        const int steps = (T_ - t0i >= TTILE) ? TTILE : (T_ - t0i);   // 64 or 24
        const float* xr = &xs[(tile & 1) * XBUF + s * LDS_STRIDE];
        float4 cur = *(const float4*)&xr[0];
        for (int tt = 0; tt < steps; tt += 4) {
            const float4 nxt = *(const float4*)&xr[tt + 4];  // pad/garbage at edge, unused
            step(cur.x);
            step(cur.y);
            step(cur.z);
            step(cur.w);
            cur = nxt;
        }
        // ---- stage prefetched tile into the other buffer (unconditional) ----
        float* xw = &xs[((tile + 1) & 1) * XBUF];
#pragma unroll
        for (int it = 0; it < 8; ++it) {
            const int r = it * 4 + rrow;
            *(float4*)&xw[r * LDS_STRIDE + ccol] = pf[it];
        }
        __syncthreads();
    }

    // ---- head: hid = H@fc_w.T + fc_b ; out = sigmoid(hid@out_w.T + out_b) ----
    if (half == 0) {
        float acc = out_b[0];
#pragma unroll
        for (int j = 0; j < 15; ++j) {
            float hid = fc_b[j];
#pragma unroll
            for (int k = 0; k < 5; ++k) hid = fmaf(H[k], fc_w[j * 5 + k], hid);
            acc = fmaf(hid, out_w[j], acc);
        }
        out[seq] = fast_rcp(1.0f + fast_exp2(-acc * LOG2E));
    }
}

extern "C" void kernel_launch(void* const* d_in, const int* in_sizes, int n_in,
                              void* d_out, int out_size, void* d_ws, size_t ws_size,
                              hipStream_t stream) {
    const float* x    = (const float*)d_in[0];
    const float* w_ih = (const float*)d_in[1];
    const float* w_hh = (const float*)d_in[2];
    const float* b_ih = (const float*)d_in[3];
    const float* b_hh = (const float*)d_in[4];
    const float* fc_w = (const float*)d_in[5];
    const float* fc_b = (const float*)d_in[6];
    const float* out_w = (const float*)d_in[7];
    const float* out_b = (const float*)d_in[8];
    float* out = (float*)d_out;

    const int N = in_sizes[0] / T_;             // 32768
    const int grid = N / SEQ_PER_BLOCK;         // 1024 blocks -> 1 wave/SIMD
    hipLaunchKernelGGL(lstm_kernel, dim3(grid), dim3(64), 0, stream,
                       x, w_ih, w_hh, b_ih, b_hh, fc_w, fc_b, out_w, out_b, out);
}